// Round 1
// 69.574 us; speedup vs baseline: 1.0353x; 1.0353x over previous
//
#include <hip/hip_runtime.h>
#include <math.h>

#define S_LEN 16384
#define L_LEN 16320
#define NF 32
#define NBLK 255            // L_LEN / 64
#define TWO_PI 6.283185307179586

// Derivation (validated numerically in the previous session):
//   out[b,l,f] = x[l+2f]  * A0(f)*sin(2pi*(b0(f)+nu(f)*l))
//              + x[l+2f+1]* A1(f)*sin(2pi*(b1(f)+nu(f)*l))
//              + x[l+2f+2]* A2(f)*sin(2pi*(b2(f)+nu(f)*l))
//              + x[l+32]  * rk[f]
// with nu = fq/16000 rev/sample and A_w from the Dirichlet closed form.
//
// v2 restructure: ALL f64 + libm-transcendental work is hoisted into a
// one-block setup kernel (it was being redone per x-block: 4 double sin()
// per block x 1020 blocks, plus 3 f64 fma/rint/cvt per OUTPUT). Setup
// writes a float table to d_ws:
//   ws[0:32)    nu        (f32, rev/sample)
//   ws[32:64)   A0
//   ws[64:96)   A1
//   ws[96:128)  A2
//   ws[128:160) rk
//   ws[160 + i*96 + {0..32,32..64,64..96})  per-block bases
//        u_w(i) = frac(b_w + nu*i*64), computed in f64, stored f32
// total = 160 + 255*96 floats = 98,560 B  (<< ws_size)
//
// Main kernel is then pure f32: phase = fmaf(nu, li, base) with li in
// [0,64) (max |phase| ~ 50 rev -> ulp 3.8e-6 rev -> output error <= 5e-4,
// negligible vs the measured 0.031 absmax), v_fract_f32 to wrap, and the
// HARDWARE v_sin_f32 (input already in revolutions) instead of libm sinf.

__global__ __launch_bounds__(256) void sineconv_setup(
    const float* __restrict__ phases, const float* __restrict__ amplitude,
    const float* __restrict__ frequency, const float* __restrict__ rk,
    float* __restrict__ ws)
{
    __shared__ double s_nu[NF], s_b0[NF], s_b1[NF], s_b2[NF];
    int t = threadIdx.x;
    if (t < NF) {
        int f = t;
        double fq  = (double)frequency[f] * 19000.0;
        double nu  = fq / 16000.0;             // revolutions per sample
        double om2 = (TWO_PI * 0.5) * nu;      // omega/2 (radians)
        double ph  = (double)phases[f];        // revolutions
        double amp = (double)amplitude[f];
        double sh  = sin(om2);
        int n0 = 32 - f, n2 = f + 1;
        double R0, R1, R2v;
        if (fabs(sh) > 1e-30) {
            double inv = 1.0 / sh;
            R0  = sin((double)n0 * om2) * inv;
            R1  = sin(32.0 * om2) * inv;
            R2v = sin((double)n2 * om2) * inv;
        } else {                               // degenerate freq (never hit here)
            R0 = n0; R1 = 32.0; R2v = n2;
        }
        s_nu[f] = nu;
        s_b0[f] = ph + nu * (0.5 * (double)(31 - f));   // start a=l,    n=32-f
        s_b1[f] = ph + nu * ((double)(32 - f) + 15.5);  // a=l+32-f,     n=32
        s_b2[f] = ph + nu * (64.0 - 0.5 * (double)f);   // a=l+64-f,     n=f+1
        ws[f]        = (float)nu;
        ws[32 + f]   = (float)(amp * R0);
        ws[64 + f]   = (float)(amp * R1);
        ws[96 + f]   = (float)(amp * R2v);
        ws[128 + f]  = rk[f];
    }
    __syncthreads();

    // Per-block frac'd phase bases: (i,f) covered exactly once.
    int f = t & 31;
    double nu = s_nu[f], b0 = s_b0[f], b1 = s_b1[f], b2 = s_b2[f];
    for (int i = (t >> 5); i < NBLK; i += 8) {
        double lw = (double)(i * 64);
        double u0 = fma(nu, lw, b0); u0 -= rint(u0);
        double u1 = fma(nu, lw, b1); u1 -= rint(u1);
        double u2 = fma(nu, lw, b2); u2 -= rint(u2);
        float* dst = ws + 160 + i * 96;
        dst[f]      = (float)u0;
        dst[32 + f] = (float)u1;
        dst[64 + f] = (float)u2;
    }
}

__global__ __launch_bounds__(256) void sineconv_main(
    const float* __restrict__ x, const float* __restrict__ ws,
    float* __restrict__ out)
{
    __shared__ float xl[128];    // x[l0 .. l0+127]; max use li+2f+2 = 127
    __shared__ float tab[256];   // {nu,A0,A1,A2,rk,u0,u1,u2}[32]

    int b  = blockIdx.y;
    int l0 = blockIdx.x * 64;
    int t  = threadIdx.x;

    if (t < 128) xl[t] = x[b * S_LEN + l0 + t];          // l0+127 <= 16381 < S_LEN
    tab[t] = (t < 160) ? ws[t] : ws[160 + blockIdx.x * 96 + (t - 160)];
    __syncthreads();

    int f  = t & 31;
    int lb = t >> 5;             // 0..7; li = lb + 8k covers 0..63 once per block
    float nuf = tab[f];
    float A0  = tab[32 + f], A1 = tab[64 + f], A2 = tab[96 + f];
    float rkf = tab[128 + f];
    float u0b = tab[160 + f], u1b = tab[192 + f], u2b = tab[224 + f];

#pragma unroll
    for (int k = 0; k < 8; ++k) {
        int li = lb + k * 8;
        float lif = (float)li;
        // phase in revolutions; v_fract wraps to [0,1); v_sin_f32 takes revs
        float u0 = __builtin_amdgcn_fractf(fmaf(nuf, lif, u0b));
        float u1 = __builtin_amdgcn_fractf(fmaf(nuf, lif, u1b));
        float u2 = __builtin_amdgcn_fractf(fmaf(nuf, lif, u2b));
        float s0 = A0 * __builtin_amdgcn_sinf(u0);
        float s1 = A1 * __builtin_amdgcn_sinf(u1);
        float s2 = A2 * __builtin_amdgcn_sinf(u2);
        float v = xl[li + 2 * f]     * s0
                + xl[li + 2 * f + 1] * s1
                + xl[li + 2 * f + 2] * s2
                + xl[li + 32]        * rkf;
        out[((b * L_LEN) + (l0 + li)) * NF + f] = v;     // wave -> contiguous 256B
    }
}

extern "C" void kernel_launch(void* const* d_in, const int* in_sizes, int n_in,
                              void* d_out, int out_size, void* d_ws, size_t ws_size,
                              hipStream_t stream) {
    const float* x    = (const float*)d_in[0];  // (4, 16384, 1)
    // d_in[1] = sine_range: analytic (t/16000), not needed
    const float* ph   = (const float*)d_in[2];  // (32, 1)
    const float* amp  = (const float*)d_in[3];  // (32, 1)
    const float* freq = (const float*)d_in[4];  // (32, 1)
    const float* rk   = (const float*)d_in[5];  // (1, 1, 32)
    float* ws  = (float*)d_ws;
    float* out = (float*)d_out;

    sineconv_setup<<<dim3(1), 256, 0, stream>>>(ph, amp, freq, rk, ws);
    sineconv_main<<<dim3(NBLK, 4), 256, 0, stream>>>(x, ws, out);
}

// Round 3
// 65.943 us; speedup vs baseline: 1.0923x; 1.0551x over previous
//
#include <hip/hip_runtime.h>
#include <math.h>

#define S_LEN 16384
#define L_LEN 16320
#define NF 32
#define NBLK 255            // L_LEN / 64

// Derivation (validated numerically in earlier rounds):
//   out[b,l,f] = x[l+2f]  * A0(f)*sin(2pi*(b0(f)+nu(f)*l))
//              + x[l+2f+1]* A1(f)*sin(2pi*(b1(f)+nu(f)*l))
//              + x[l+2f+2]* A2(f)*sin(2pi*(b2(f)+nu(f)*l))
//              + x[l+32]  * rk[f]
// with nu = fq/16000 rev/sample and A_w from the Dirichlet closed form.
//
// v3: SINGLE dispatch (R1 showed the timed loop is fixed-cost dominated;
// the 2nd launch ate the compute win). Per-block setup runs in lanes
// t<32 using f64 fma/frac for phase accuracy (|b_w + nu*l0| up to ~3e3
// rev; f32 would give ~0.03 output error) but HARDWARE v_sin_f32 for all
// transcendentals (args frac'd to [-0.5,0.5] rev in f64 first) — no libm.
//
// Inner loop: zero transcendentals per output. Angle addition
//   A_w*sin(2pi*(phi_w + nu*li)) = P_w*cos(th) + Q_w*sin(th),
//   P_w = A_w*sin(2pi*phi_w), Q_w = A_w*cos(2pi*phi_w), th = 2pi*nu*li
// with li = lb + 8k per thread: (sin th, cos th) initialized once per
// thread (2 hw trans ops) and advanced by the fixed rotation
// Delta = 2pi*frac(8*nu) via 4 FMA per k (7 f32 rotations -> ~1e-6 rev
// drift, negligible vs the 0.031 absmax).

__device__ __forceinline__ float sinrev64(double rev) {
    // sin(2pi*rev): exact f64 wrap to [-0.5,0.5], then hw v_sin_f32
    double u = rev - rint(rev);
    return __builtin_amdgcn_sinf((float)u);
}
__device__ __forceinline__ float cosrev64(double rev) {
    double u = rev - rint(rev);
    return __builtin_amdgcn_cosf((float)u);
}

__global__ __launch_bounds__(256) void sineconv_fused(
    const float* __restrict__ x, const float* __restrict__ phases,
    const float* __restrict__ amplitude, const float* __restrict__ frequency,
    const float* __restrict__ rk, float* __restrict__ out)
{
    __shared__ float xl[128];        // x[l0 .. l0+127]; max use li+2f+2 = 127
    __shared__ float tab[10 * NF];   // {nu,P0,Q0,P1,Q1,P2,Q2,rk,sd,cd}[32]

    int b  = blockIdx.y;
    int l0 = blockIdx.x * 64;
    int t  = threadIdx.x;

    if (t < 128) xl[t] = x[b * S_LEN + l0 + t];   // l0+127 <= 16381 < S_LEN

    if (t < NF) {
        int f = t;
        double fq   = (double)frequency[f] * 19000.0;
        double nu   = fq * (1.0 / 16000.0);        // revolutions per sample
        double hrev = 0.5 * nu;                    // omega/(2*2pi) = nu/2 rev
        double ph   = (double)phases[f];           // revolutions
        float  amp  = amplitude[f];
        float  sh   = sinrev64(hrev);
        int n0 = 32 - f, n2 = f + 1;
        float R0, R1, R2;
        if (fabsf(sh) > 1e-30f) {
            float inv = 1.0f / sh;
            R0 = sinrev64((double)n0 * hrev) * inv;
            R1 = sinrev64(32.0 * hrev) * inv;
            R2 = sinrev64((double)n2 * hrev) * inv;
        } else {                                   // degenerate freq (never hit)
            R0 = (float)n0; R1 = 32.0f; R2 = (float)n2;
        }
        float A0 = amp * R0, A1 = amp * R1, A2 = amp * R2;

        double b0 = ph + nu * (0.5 * (double)(31 - f));   // start a=l,  n=32-f
        double b1 = ph + nu * ((double)(32 - f) + 15.5);  // a=l+32-f,   n=32
        double b2 = ph + nu * (64.0 - 0.5 * (double)f);   // a=l+64-f,   n=f+1
        double lw = (double)l0;
        double u0 = fma(nu, lw, b0); u0 -= rint(u0);      // phi_w, exact wrap
        double u1 = fma(nu, lw, b1); u1 -= rint(u1);
        double u2 = fma(nu, lw, b2); u2 -= rint(u2);

        float f0 = (float)u0, f1 = (float)u1, f2 = (float)u2;
        tab[f]            = (float)nu;                       // nu (rev/sample)
        tab[NF * 1 + f]   = A0 * __builtin_amdgcn_sinf(f0);  // P0
        tab[NF * 2 + f]   = A0 * __builtin_amdgcn_cosf(f0);  // Q0
        tab[NF * 3 + f]   = A1 * __builtin_amdgcn_sinf(f1);  // P1
        tab[NF * 4 + f]   = A1 * __builtin_amdgcn_cosf(f1);  // Q1
        tab[NF * 5 + f]   = A2 * __builtin_amdgcn_sinf(f2);  // P2
        tab[NF * 6 + f]   = A2 * __builtin_amdgcn_cosf(f2);  // Q2
        tab[NF * 7 + f]   = rk[f];
        double d8 = 8.0 * nu;                                // k-step: Delta=8*nu
        tab[NF * 8 + f]   = sinrev64(d8);                    // sd
        tab[NF * 9 + f]   = cosrev64(d8);                    // cd
    }
    __syncthreads();

    int f  = t & 31;
    int lb = t >> 5;             // 0..7; li = lb + 8k covers 0..63 once per block
    float nuf = tab[f];
    float P0 = tab[NF * 1 + f], Q0 = tab[NF * 2 + f];
    float P1 = tab[NF * 3 + f], Q1 = tab[NF * 4 + f];
    float P2 = tab[NF * 5 + f], Q2 = tab[NF * 6 + f];
    float rkf = tab[NF * 7 + f];
    float sd = tab[NF * 8 + f], cd = tab[NF * 9 + f];

    // th = 2pi*nu*lb at k=0 (nu*lb <= ~6 rev: f32 wrap fine at this scale)
    float u0t = __builtin_amdgcn_fractf(nuf * (float)lb);
    float st = __builtin_amdgcn_sinf(u0t);
    float ct = __builtin_amdgcn_cosf(u0t);

#pragma unroll
    for (int k = 0; k < 8; ++k) {
        int li = lb + k * 8;
        // A_w*sin(2pi*(phi_w + nu*li)) = P_w*ct + Q_w*st
        float s0 = fmaf(P0, ct, Q0 * st);
        float s1 = fmaf(P1, ct, Q1 * st);
        float s2 = fmaf(P2, ct, Q2 * st);
        float v = xl[li + 2 * f]     * s0
                + xl[li + 2 * f + 1] * s1
                + xl[li + 2 * f + 2] * s2
                + xl[li + 32]        * rkf;
        out[((b * L_LEN) + (l0 + li)) * NF + f] = v;  // wave -> contiguous 256B
        // rotate th += 2pi*frac(8*nu)
        float nst = fmaf(st, cd, ct * sd);
        float nct = fmaf(ct, cd, -st * sd);
        st = nst; ct = nct;
    }
}

extern "C" void kernel_launch(void* const* d_in, const int* in_sizes, int n_in,
                              void* d_out, int out_size, void* d_ws, size_t ws_size,
                              hipStream_t stream) {
    const float* x    = (const float*)d_in[0];  // (4, 16384, 1)
    // d_in[1] = sine_range: analytic (t/16000), not needed
    const float* ph   = (const float*)d_in[2];  // (32, 1)
    const float* amp  = (const float*)d_in[3];  // (32, 1)
    const float* freq = (const float*)d_in[4];  // (32, 1)
    const float* rk   = (const float*)d_in[5];  // (1, 1, 32)
    float* out = (float*)d_out;

    sineconv_fused<<<dim3(NBLK, 4), 256, 0, stream>>>(x, ph, amp, freq, rk, out);
}